// Round 1
// baseline (1766.020 us; speedup 1.0000x reference)
//
#include <hip/hip_runtime.h>
#include <math.h>

#define N 4096
#define D 512
#define L 128
#define PARTS 8
#define PARTJ (N / PARTS)   // 512
#define TI 128
#define TJ 64
#define KD 32
#define AS_STRIDE (TI + 4)  // 132
#define BS_STRIDE (TJ + 4)  // 68
#define DS_STRIDE (TJ + 4)  // 68

// Insert v into ascending sorted tk[0..15], dropping the old max.
// Caller guarantees v < tk[15].
__device__ __forceinline__ void topk_insert(float (&tk)[16], float v) {
  float x = v;
#pragma unroll
  for (int k = 0; k < 16; ++k) {
    float lo = fminf(x, tk[k]);
    float hi = fmaxf(x, tk[k]);
    tk[k] = lo;
    x = hi;
  }
}

// rec = latent @ W + b ; grid (N/8, 2), block 256. y==0 -> test, y==1 -> train
__global__ __launch_bounds__(256) void linear_kernel(
    const float* __restrict__ lat_test, const float* __restrict__ lat_train,
    const float* __restrict__ W, const float* __restrict__ bias,
    float* __restrict__ rec_test, float* __restrict__ rec_train) {
  const float* __restrict__ lat = blockIdx.y ? lat_train : lat_test;
  float* __restrict__ out = blockIdx.y ? rec_train : rec_test;
  const int r0 = blockIdx.x * 8;
  const int t = threadIdx.x;

  __shared__ float ls[8 * L];  // 8 latent rows
  {
    float4 v = *(const float4*)(lat + (size_t)r0 * L + t * 4);
    *(float4*)&ls[t * 4] = v;
  }
  __syncthreads();

  float acc[8][2];
#pragma unroll
  for (int r = 0; r < 8; ++r) { acc[r][0] = 0.f; acc[r][1] = 0.f; }

#pragma unroll 4
  for (int l = 0; l < L; ++l) {
    float w0 = W[l * D + t];
    float w1 = W[l * D + t + 256];
#pragma unroll
    for (int r = 0; r < 8; ++r) {
      float x = ls[r * L + l];
      acc[r][0] = fmaf(x, w0, acc[r][0]);
      acc[r][1] = fmaf(x, w1, acc[r][1]);
    }
  }
  float b0 = bias[t], b1 = bias[t + 256];
#pragma unroll
  for (int r = 0; r < 8; ++r) {
    out[(size_t)(r0 + r) * D + t] = acc[r][0] + b0;
    out[(size_t)(r0 + r) * D + t + 256] = acc[r][1] + b1;
  }
}

// Fused L1-cdist + per-row top-16 (smallest distances) over one j-part.
// grid (N/TI, PARTS, 2), block 256. z==0: B=gt_vals, z==1: B=rec_train.
// cand layout: [mat][part][row][16], each 16-list sorted ascending.
__global__ __launch_bounds__(256) void dist_topk_kernel(
    const float* __restrict__ Arec, const float* __restrict__ Bgt,
    const float* __restrict__ Btr, float* __restrict__ cand) {
  const int itile = blockIdx.x;
  const int part = blockIdx.y;
  const int mat = blockIdx.z;
  const float* __restrict__ B = mat ? Btr : Bgt;
  const int i0 = itile * TI;
  const int jbase = part * PARTJ;

  __shared__ float As[KD * AS_STRIDE];   // 16.5 KB, [d][i] transposed
  __shared__ float Bs[KD * BS_STRIDE];   // 8.5 KB,  [d][j] transposed
  __shared__ float distS[TI * DS_STRIDE];  // 34 KB

  const int tid = threadIdx.x;
  const int tx = tid & 15;   // j = 4*tx
  const int ty = tid >> 4;   // i = 8*ty

  float tk[16];
#pragma unroll
  for (int k = 0; k < 16; ++k) tk[k] = 3.0e38f;

  for (int jc = 0; jc < PARTJ; jc += TJ) {
    float acc[8][4];
#pragma unroll
    for (int r = 0; r < 8; ++r)
#pragma unroll
      for (int c = 0; c < 4; ++c) acc[r][c] = 0.f;

    for (int d0 = 0; d0 < D; d0 += KD) {
      __syncthreads();
      // stage A: TI x KD = 4096 floats, 4 float4 per thread, transposed store
#pragma unroll
      for (int s = 0; s < 4; ++s) {
        int f4 = tid + s * 256;
        int r = f4 >> 3;    // 0..127
        int c4 = f4 & 7;    // float4 within the 32-wide d-chunk
        float4 v = *(const float4*)(Arec + (size_t)(i0 + r) * D + d0 + c4 * 4);
        As[(4 * c4 + 0) * AS_STRIDE + r] = v.x;
        As[(4 * c4 + 1) * AS_STRIDE + r] = v.y;
        As[(4 * c4 + 2) * AS_STRIDE + r] = v.z;
        As[(4 * c4 + 3) * AS_STRIDE + r] = v.w;
      }
      // stage B: TJ x KD = 2048 floats, 2 float4 per thread
#pragma unroll
      for (int s = 0; s < 2; ++s) {
        int f4 = tid + s * 256;
        int r = f4 >> 3;    // 0..63
        int c4 = f4 & 7;
        float4 v = *(const float4*)(B + (size_t)(jbase + jc + r) * D + d0 + c4 * 4);
        Bs[(4 * c4 + 0) * BS_STRIDE + r] = v.x;
        Bs[(4 * c4 + 1) * BS_STRIDE + r] = v.y;
        Bs[(4 * c4 + 2) * BS_STRIDE + r] = v.z;
        Bs[(4 * c4 + 3) * BS_STRIDE + r] = v.w;
      }
      __syncthreads();

#pragma unroll
      for (int d = 0; d < KD; ++d) {
        float4 a0 = *(const float4*)&As[d * AS_STRIDE + 8 * ty];
        float4 a1 = *(const float4*)&As[d * AS_STRIDE + 8 * ty + 4];
        float4 bv4 = *(const float4*)&Bs[d * BS_STRIDE + 4 * tx];
        float av[8] = {a0.x, a0.y, a0.z, a0.w, a1.x, a1.y, a1.z, a1.w};
        float bv[4] = {bv4.x, bv4.y, bv4.z, bv4.w};
#pragma unroll
        for (int r = 0; r < 8; ++r)
#pragma unroll
          for (int c = 0; c < 4; ++c) acc[r][c] += fabsf(av[r] - bv[c]);
      }
    }

    __syncthreads();
#pragma unroll
    for (int r = 0; r < 8; ++r)
#pragma unroll
      for (int c = 0; c < 4; ++c)
        distS[(8 * ty + r) * DS_STRIDE + 4 * tx + c] = acc[r][c];
    __syncthreads();

    if (tid < TI) {
#pragma unroll 1
      for (int j4 = 0; j4 < TJ / 4; ++j4) {
        float4 v = *(const float4*)&distS[tid * DS_STRIDE + j4 * 4];
        if (v.x < tk[15]) topk_insert(tk, v.x);
        if (v.y < tk[15]) topk_insert(tk, v.y);
        if (v.z < tk[15]) topk_insert(tk, v.z);
        if (v.w < tk[15]) topk_insert(tk, v.w);
      }
    }
  }

  if (tid < TI) {
    const int row = i0 + tid;
    float* dst = cand + ((size_t)((mat * PARTS + part) * N) + row) * 16;
#pragma unroll
    for (int k = 0; k < 16; ++k) dst[k] = tk[k];
  }
}

// Merge 8 sorted 16-lists per (mat,row); score = mean of 16 reciprocals.
__global__ __launch_bounds__(256) void merge_kernel(
    const float* __restrict__ cand, float* __restrict__ scores) {
  const int gid = blockIdx.x * 256 + threadIdx.x;  // 0..8191
  if (gid >= 2 * N) return;
  const int m = gid >> 12;
  const int row = gid & (N - 1);

  float tk[16];
#pragma unroll
  for (int k = 0; k < 16; ++k) tk[k] = 3.0e38f;

  for (int p = 0; p < PARTS; ++p) {
    const float* lp = cand + ((size_t)((m * PARTS + p) * N) + row) * 16;
#pragma unroll 1
    for (int k = 0; k < 16; ++k) {
      float v = lp[k];
      if (v >= tk[15]) break;  // sorted ascending: rest are larger
      topk_insert(tk, v);
    }
  }
  float s = 0.f;
#pragma unroll
  for (int k = 0; k < 16; ++k) s += 1.0f / tk[k];
  scores[(size_t)m * N + row] = s * (1.0f / 16.0f);
}

// losses = relu(neg - pos); huber(delta=1) vs 0; mean. Single block.
__global__ __launch_bounds__(256) void loss_kernel(
    const float* __restrict__ scores, float* __restrict__ out) {
  const int tid = threadIdx.x;
  float s = 0.f;
  for (int i = tid; i < N; i += 256) {
    float l = scores[N + i] - scores[i];
    l = fmaxf(l, 0.f);
    s += (l <= 1.f) ? 0.5f * l * l : (l - 0.5f);
  }
#pragma unroll
  for (int off = 32; off > 0; off >>= 1) s += __shfl_down(s, off, 64);
  __shared__ float ws[4];
  if ((tid & 63) == 0) ws[tid >> 6] = s;
  __syncthreads();
  if (tid == 0) {
    float t = ws[0] + ws[1] + ws[2] + ws[3];
    out[0] = t * (1.0f / (float)N);
  }
}

extern "C" void kernel_launch(void* const* d_in, const int* in_sizes, int n_in,
                              void* d_out, int out_size, void* d_ws, size_t ws_size,
                              hipStream_t stream) {
  const float* gt_vals = (const float*)d_in[0];       // [N, D]
  const float* train_latent = (const float*)d_in[1];  // [N, L]
  const float* test_latent = (const float*)d_in[2];   // [N, L]
  const float* W = (const float*)d_in[3];             // [L, D]
  const float* b = (const float*)d_in[4];             // [D]
  float* out = (float*)d_out;

  char* ws = (char*)d_ws;
  float* rec_test = (float*)(ws);                                  // 8 MB
  float* rec_train = (float*)(ws + (size_t)8388608);               // 8 MB
  float* cand = (float*)(ws + (size_t)16777216);                   // 4 MB
  float* scores = (float*)(ws + (size_t)16777216 + 4194304);       // 32 KB

  linear_kernel<<<dim3(N / 8, 2), 256, 0, stream>>>(
      test_latent, train_latent, W, b, rec_test, rec_train);
  dist_topk_kernel<<<dim3(N / TI, PARTS, 2), 256, 0, stream>>>(
      rec_test, gt_vals, rec_train, cand);
  merge_kernel<<<(2 * N) / 256, 256, 0, stream>>>(cand, scores);
  loss_kernel<<<1, 256, 0, stream>>>(scores, out);
}